// Round 19
// baseline (171.084 us; speedup 1.0000x reference)
//
#include <hip/hip_runtime.h>
#include <hip/hip_fp16.h>
#include <math.h>

#define N_NODES 100000
#define N_EDGES 1600000
#define F0 32
#define F1 16
#define F2 8
#define NCLS 6
#define NGRAPH 64

#define BSH  7         // bucket = 128 nodes (power of 2 -> exact split)
#define BSZ  128       // nodes per bucket
#define NBUK 782       // ceil(100000/128) -> 3.05 blocks/CU (tail ~5%, was 25%)
#define CAPB 2560      // edge cap per bucket (mean 2046, sigma 45 -> +11 sigma)
#define EPB  2047      // edges per xpart chunk: ceil(1600000/782)
#define XEIT 4         // xpart stage iterations: 4*512 = 2048 >= EPB
#define NPW  129       // np_g stride per bucket
#define HPAD 1024      // padded histogram width (>= NBUK)

// unpack 8 fp16 (uint4) into 8 float accumulators
__device__ __forceinline__ void acc8h(float* acc, uint4 v) {
    const __half2* p = reinterpret_cast<const __half2*>(&v);
#pragma unroll
    for (int q = 0; q < 4; q++) {
        float2 f = __half22float2(p[q]);
        acc[2*q]   += f.x;
        acc[2*q+1] += f.y;
    }
}
// unpack 4 fp16 (uint2) into 4 float accumulators
__device__ __forceinline__ void acc4h(float* acc, uint2 v) {
    const __half2* p = reinterpret_cast<const __half2*>(&v);
#pragma unroll
    for (int q = 0; q < 2; q++) {
        float2 f = __half22float2(p[q]);
        acc[2*q]   += f.x;
        acc[2*q+1] += f.y;
    }
}

// ====== kernel 1: node-transform (x@W1a -> fp16) + write-coalesced partition ======
// r19: 782 chunks (tail-balance); 1024-wide hist scan, 2 entries/thread
__global__ __launch_bounds__(512) void xpart_k(
    const float* __restrict__ x, const float* __restrict__ W1a,
    uint4* __restrict__ xw1h, const int* __restrict__ ei,
    int* __restrict__ gcursor, int* __restrict__ pairs) {
    __shared__ float sW[F0 * F1];
    __shared__ int hist[HPAD];             // counts -> excl (reused)
    __shared__ int gbase[HPAD];
    __shared__ int lcur[HPAD];
    __shared__ int wsum[8];
    __shared__ int lpk[2048];              // chunk edges, bucket-sorted (packed)
    __shared__ unsigned short lb[2048];    // bucket id per sorted edge
    int t = threadIdx.x, c = blockIdx.x;
    int lane = t & 63, w = t >> 6;
    for (int i = t; i < F0 * F1; i += 512) sW[i] = W1a[i];
    hist[t] = 0; hist[t + 512] = 0;
    __syncthreads();

    // --- stage src+dst in registers + chunk histogram ---
    int base = c * EPB;
    int dreg[XEIT], sreg[XEIT];
#pragma unroll
    for (int it = 0; it < XEIT; it++) {
        int li = it * 512 + t;
        int i = base + li;
        dreg[it] = -1;
        if (li < EPB && i < N_EDGES) {
            sreg[it] = ei[i];
            int d = ei[N_EDGES + i];
            dreg[it] = d;
            atomicAdd(&hist[d >> BSH], 1);
        }
    }

    // --- node projection: 128 nodes/block, lane pairs (threads 0..255) ---
    if (t < 256) {
        int h = t & 1, s = t >> 1;         // s in [0,128)
        int n = c * BSZ + s;
        if (n < N_NODES) {
            const float4* xp = reinterpret_cast<const float4*>(x) + n * 8 + h * 4;
            float xi[16];
#pragma unroll
            for (int q = 0; q < 4; q++) {
                float4 v = xp[q];
                xi[4*q] = v.x; xi[4*q+1] = v.y; xi[4*q+2] = v.z; xi[4*q+3] = v.w;
            }
            float o[F1];
#pragma unroll
            for (int j = 0; j < F1; j++) {
                float s2 = 0.0f;
#pragma unroll
                for (int k = 0; k < 16; k++) s2 += xi[k] * sW[(16*h + k) * F1 + j];
                o[j] = s2;
            }
#pragma unroll
            for (int j = 0; j < F1; j++) o[j] += __shfl_xor(o[j], 1); // pair-combine
            union { __half2 h2[4]; uint4 u4; } pk;
#pragma unroll
            for (int jj = 0; jj < 4; jj++)
                pk.h2[jj] = __float22half2_rn(make_float2(o[8*h + 2*jj],
                                                          o[8*h + 2*jj + 1]));
            xw1h[n * 2 + h] = pk.u4;       // 16B/lane, pair-coalesced
        }
    }
    __syncthreads();

    // --- wave-shfl scan of 1024-wide hist: 2 entries per thread ---
    int h0 = hist[2*t], h1 = hist[2*t + 1];
    int v = h0 + h1;
#pragma unroll
    for (int off = 1; off < 64; off <<= 1) {
        int u = __shfl_up(v, off);
        if (lane >= off) v += u;
    }
    if (lane == 63) wsum[w] = v;
    __syncthreads();
    int woff = 0;
    for (int i = 0; i < w; i++) woff += wsum[i];
    int exPair = v + woff - (h0 + h1);     // exclusive prefix of bucket 2t
    {
        int b = 2*t;
        lcur[b] = exPair;
        gbase[b] = (b < NBUK) ? (b * CAPB + (h0 ? atomicAdd(&gcursor[b], h0) : 0))
                              : 0;
        hist[b] = exPair;
    }
    {
        int b = 2*t + 1;
        int ex = exPair + h0;
        lcur[b] = ex;
        gbase[b] = (b < NBUK) ? (b * CAPB + (h1 ? atomicAdd(&gcursor[b], h1) : 0))
                              : 0;
        hist[b] = ex;
    }
    __syncthreads();

    // --- place staged edges into LDS, sorted by bucket (pure LDS ops) ---
#pragma unroll
    for (int it = 0; it < XEIT; it++) {
        int d = dreg[it];
        if (d >= 0) {
            int b = d >> BSH;
            int slot = atomicAdd(&lcur[b], 1);
            lpk[slot] = ((d & (BSZ - 1)) << 17) | sreg[it];
            lb[slot] = (unsigned short)b;
        }
    }
    __syncthreads();

    // --- coalesced write-out: consecutive i -> consecutive addr within runs ---
    int tot = min(EPB, N_EDGES - base);
    for (int i = t; i < tot; i += 512) {
        int b = lb[i];
        int gpos = gbase[b] + (i - hist[b]);
        if (gpos < (b + 1) * CAPB)         // overflow guard (~never taken)
            pairs[gpos] = lpk[i];
    }
}

// ==== kernel 2: per-bucket counting sort (LDS, double-buffered) + gin1 ====
// r19: 782 blocks x 256 threads; 128-node buckets; gather = 2 lanes x 128 nodes
__global__ __launch_bounds__(256) void sortgin1_k(
    const uint4* __restrict__ xw1h, const int* __restrict__ pairs,
    const int* __restrict__ gcursor,
    const float* __restrict__ b1a, const float* __restrict__ W1b,
    const float* __restrict__ b1b, const float* __restrict__ W2a,
    uint2* __restrict__ h1wh, int* __restrict__ srcs,
    int* __restrict__ np_g) {
    __shared__ int hist[BSZ];
    __shared__ int cur[BSZ];
    __shared__ int np[BSZ + 1];
    __shared__ int wsum2[2];
    __shared__ int srcs_l[CAPB];           // staged packed pairs
    __shared__ int srcs_s[CAPB];           // sorted srcs
    __shared__ float sW1b[F1 * F1];
    __shared__ float sW2a[F1 * F2];
    __shared__ float sb1a[F1], sb1b[F1];
    int t = threadIdx.x, b = blockIdx.x;
    int lane = t & 63, w = t >> 6;
    if (t < F1 * F1) sW1b[t] = W1b[t];
    if (t < F1 * F2) sW2a[t] = W2a[t];
    if (t < F1) { sb1a[t] = b1a[t]; sb1b[t] = b1b[t]; }
    if (t < BSZ) hist[t] = 0;
    __syncthreads();

    int cnt = min(gcursor[b], CAPB);
    int pb = b * CAPB;
    // hist + stage packed pairs into LDS (single global read of pairs)
    for (int i = t; i < cnt; i += 256) {
        int p = pairs[pb + i];
        srcs_l[i] = p;
        atomicAdd(&hist[p >> 17], 1);
    }
    __syncthreads();

    // --- wave-shfl inclusive scan of hist (128 wide: waves 0-1) ---
    int cntv = (t < BSZ) ? hist[t] : 0;
    int v = cntv;
    if (t < BSZ) {
#pragma unroll
        for (int off = 1; off < 64; off <<= 1) {
            int u = __shfl_up(v, off);
            if (lane >= off) v += u;
        }
        if (lane == 63) wsum2[w] = v;
    }
    __syncthreads();
    if (t < BSZ) {
        int woff = (w == 1) ? wsum2[0] : 0;
        int excl = v + woff - cntv;
        np[t] = excl;
        cur[t] = excl;
        np_g[b * NPW + t] = excl;
        if (t == 0) { np[BSZ] = cnt; np_g[b * NPW + BSZ] = cnt; }
    }
    __syncthreads();

    // scatter into second buffer (no read/write race)
    for (int i = t; i < cnt; i += 256) {
        int p = srcs_l[i];
        int pos = atomicAdd(&cur[p >> 17], 1);
        srcs_s[pos] = p & 0x1FFFF;
    }
    __syncthreads();
    // coalesced persist for gin2: consecutive lanes -> consecutive addresses
    for (int i = t; i < cnt; i += 256) srcs[pb + i] = srcs_s[i];

    // ---- layer-1 gather: 2 lanes/node x 128 nodes = 256 threads exactly ----
    int h = t & 1, slot = t >> 1;
    int n = b * BSZ + slot;
    if (n >= N_NODES) return;
    int e  = np[slot];
    int e1 = np[slot + 1];

    float acc[8];
#pragma unroll
    for (int k = 0; k < 8; k++) acc[k] = 0.0f;
    for (; e + 4 <= e1; e += 4) {                 // 4 rows in flight
        int s0 = srcs_s[e], s1 = srcs_s[e+1], s2 = srcs_s[e+2], s3 = srcs_s[e+3];
        uint4 v0 = xw1h[s0 * 2 + h];
        uint4 v1 = xw1h[s1 * 2 + h];
        uint4 v2 = xw1h[s2 * 2 + h];
        uint4 v3 = xw1h[s3 * 2 + h];
        acc8h(acc, v0); acc8h(acc, v1); acc8h(acc, v2); acc8h(acc, v3);
    }
    for (; e < e1; e++) acc8h(acc, xw1h[srcs_s[e] * 2 + h]);
    acc8h(acc, xw1h[n * 2 + h]);                  // self term

    float u[8];
#pragma unroll
    for (int k = 0; k < 8; k++) u[k] = fmaxf(acc[k] + sb1a[8*h + k], 0.0f);

    float p[F1];
#pragma unroll
    for (int j = 0; j < F1; j++) {
        float s = 0.0f;
#pragma unroll
        for (int k = 0; k < 8; k++) s += u[k] * sW1b[(8*h + k) * F1 + j];
        p[j] = s;
    }
#pragma unroll
    for (int j = 0; j < F1; j++) p[j] += __shfl_xor(p[j], 1);   // pair-combine
    float hh[F1];
#pragma unroll
    for (int j = 0; j < F1; j++) hh[j] = fmaxf(p[j] + sb1b[j], 0.0f); // relu∘relu

    float o[4];                                   // lane h owns outputs 4h..4h+3
#pragma unroll
    for (int jj = 0; jj < 4; jj++) {
        int j = 4*h + jj;
        float s = 0.0f;
#pragma unroll
        for (int k = 0; k < F1; k++) s += hh[k] * sW2a[k * F2 + j];
        o[jj] = s;
    }
    union { __half2 h2[2]; uint2 u2; } pk;
    pk.h2[0] = __float22half2_rn(make_float2(o[0], o[1]));
    pk.h2[1] = __float22half2_rn(make_float2(o[2], o[3]));
    h1wh[n * 2 + h] = pk.u2;                      // 8B/lane, pair-coalesced
}

// ==== kernel 3: layer-2 gather fp16 (2 lanes/node, 8B/lane) + MLP2 + pool ====
__global__ __launch_bounds__(256) void gin2pool_k(
    const uint2* __restrict__ h1wh, const int* __restrict__ np_g,
    const int* __restrict__ srcs, const float* __restrict__ b2a,
    const float* __restrict__ W2b, const float* __restrict__ b2b,
    const int* __restrict__ batch, float* __restrict__ gsum,
    float* __restrict__ gcnt) {
    __shared__ float sW2b[F2 * F2];
    __shared__ float sb2a[F2];
    __shared__ float sb2b[F2];
    __shared__ float ls[NGRAPH * F2];   // 512 > blockDim -> strided loops (r5 lesson)
    __shared__ float lc[NGRAPH];
    int t = threadIdx.x;
    if (t < F2 * F2) sW2b[t] = W2b[t];
    if (t < F2) { sb2a[t] = b2a[t]; sb2b[t] = b2b[t]; }
    for (int i = t; i < NGRAPH * F2; i += 256) ls[i] = 0.0f;
    if (t < NGRAPH) lc[t] = 0.0f;
    __syncthreads();

    int h = t & 1, slot = t >> 1;                 // 128 nodes per block
    int n = blockIdx.x * BSZ + slot;
    if (n < N_NODES) {
        int b = n >> BSH, sl = n & (BSZ - 1);
        int pb = b * CAPB;
        int e  = pb + np_g[b * NPW + sl];
        int e1 = pb + np_g[b * NPW + sl + 1];

        float acc[4];
#pragma unroll
        for (int k = 0; k < 4; k++) acc[k] = 0.0f;
        for (; e + 4 <= e1; e += 4) {
            int s0 = srcs[e], s1 = srcs[e+1], s2 = srcs[e+2], s3 = srcs[e+3];
            uint2 v0 = h1wh[s0 * 2 + h];
            uint2 v1 = h1wh[s1 * 2 + h];
            uint2 v2 = h1wh[s2 * 2 + h];
            uint2 v3 = h1wh[s3 * 2 + h];
            acc4h(acc, v0); acc4h(acc, v1); acc4h(acc, v2); acc4h(acc, v3);
        }
        for (; e < e1; e++) acc4h(acc, h1wh[srcs[e] * 2 + h]);
        acc4h(acc, h1wh[n * 2 + h]);              // self term

        float u[4];
#pragma unroll
        for (int k = 0; k < 4; k++) u[k] = fmaxf(acc[k] + sb2a[4*h + k], 0.0f);

        float p[F2];
#pragma unroll
        for (int j = 0; j < F2; j++) {
            float s = 0.0f;
#pragma unroll
            for (int k = 0; k < 4; k++) s += u[k] * sW2b[(4*h + k) * F2 + j];
            p[j] = s;
        }
#pragma unroll
        for (int j = 0; j < F2; j++) p[j] += __shfl_xor(p[j], 1);

        int g = batch[n];
#pragma unroll
        for (int jj = 0; jj < 4; jj++) {          // lane h flushes feats 4h..4h+3
            int j = 4*h + jj;
            float v = fmaxf(p[j] + sb2b[j], 0.0f);
            atomicAdd(&ls[g * F2 + j], v);
        }
        if (h == 0) atomicAdd(&lc[g], 1.0f);
    }
    __syncthreads();
    for (int i = t; i < NGRAPH * F2; i += 256)
        if (ls[i] != 0.0f) atomicAdd(&gsum[i], ls[i]);
    if (t < NGRAPH && lc[t] != 0.0f) atomicAdd(&gcnt[t], lc[t]);
}

// ---------------- final: pooled -> FC -> log_softmax ----------------
__global__ void final_k(const float* __restrict__ gsum,
                        const float* __restrict__ gcnt,
                        const float* __restrict__ Wfc, const float* __restrict__ bfc,
                        float* __restrict__ out) {
    int g = threadIdx.x;
    if (g >= NGRAPH) return;
    float cnt = fmaxf(gcnt[g], 1.0f);
    float p[F2];
#pragma unroll
    for (int f = 0; f < F2; f++) p[f] = gsum[g * F2 + f] / cnt;
    float l[NCLS];
#pragma unroll
    for (int c = 0; c < NCLS; c++) {
        float s = bfc[c];
#pragma unroll
        for (int f = 0; f < F2; f++) s += p[f] * Wfc[f * NCLS + c];
        l[c] = s;
    }
    float m = -INFINITY;
#pragma unroll
    for (int c = 0; c < NCLS; c++) m = fmaxf(m, l[c]);
    float s = 0.0f;
#pragma unroll
    for (int c = 0; c < NCLS; c++) s += expf(l[c] - m);
    float lse = m + logf(s);
#pragma unroll
    for (int c = 0; c < NCLS; c++) out[g * NCLS + c] = l[c] - lse;
}

extern "C" void kernel_launch(void* const* d_in, const int* in_sizes, int n_in,
                              void* d_out, int out_size, void* d_ws, size_t ws_size,
                              hipStream_t stream) {
    const float* x    = (const float*)d_in[0];
    const int*   ei   = (const int*)d_in[1];   // [2, N_EDGES]
    const int*   batch= (const int*)d_in[2];   // [N_NODES], sorted
    const float* W1a  = (const float*)d_in[3];
    const float* b1a  = (const float*)d_in[4];
    const float* W1b  = (const float*)d_in[5];
    const float* b1b  = (const float*)d_in[6];
    const float* W2a  = (const float*)d_in[7];
    const float* b2a  = (const float*)d_in[8];
    const float* W2b  = (const float*)d_in[9];
    const float* b2b  = (const float*)d_in[10];
    const float* Wfc  = (const float*)d_in[11];
    const float* bfc  = (const float*)d_in[12];
    float* out = (float*)d_out;

    // workspace layout (4-byte units), ~21.3 MB
    float* ws      = (float*)d_ws;
    uint4* xw1h    = (uint4*)ws;                           // N_NODES*2 uint4 (fp16)
    uint2* h1wh    = (uint2*)(ws + (size_t)N_NODES * 8);   // N_NODES*2 uint2 (fp16)
    int*   pairs   = (int*)(ws + (size_t)N_NODES * 12);    // NBUK*CAPB = 2001920
    int*   srcs    = pairs + (size_t)NBUK * CAPB;          // NBUK*CAPB
    int*   np_g    = srcs + (size_t)NBUK * CAPB;           // NBUK*NPW = 100878
    int*   gcursor = np_g + (size_t)NBUK * NPW + 2;        // 1024  (memset)
    float* gsum    = (float*)(gcursor + 1024);             // 512   (memset)
    float* gcnt    = gsum + NGRAPH * F2;                   // 64    (memset)

    // one tiny memset: gcursor + gsum + gcnt adjacent
    hipMemsetAsync(gcursor, 0, (1024 + NGRAPH * F2 + NGRAPH) * sizeof(int), stream);

    xpart_k<<<NBUK, 512, 0, stream>>>(x, W1a, xw1h, ei, gcursor, pairs);
    sortgin1_k<<<NBUK, 256, 0, stream>>>(xw1h, pairs, gcursor,
                                         b1a, W1b, b1b, W2a,
                                         h1wh, srcs, np_g);
    gin2pool_k<<<(N_NODES + BSZ - 1) / BSZ, 256, 0, stream>>>(h1wh, np_g, srcs,
                                                              b2a, W2b, b2b, batch,
                                                              gsum, gcnt);
    final_k<<<1, 64, 0, stream>>>(gsum, gcnt, Wfc, bfc, out);
}

// Round 20
// 145.832 us; speedup vs baseline: 1.1732x; 1.1732x over previous
//
#include <hip/hip_runtime.h>
#include <hip/hip_fp16.h>
#include <math.h>

#define N_NODES 100000
#define N_EDGES 1600000
#define F0 32
#define F1 16
#define F2 8
#define NCLS 6
#define NGRAPH 64

#define BSH  8         // bucket = 256 nodes (power of 2 -> exact split)
#define BSZ  256       // nodes per bucket
#define NBUK 391       // ceil(100000/256)  [r19's 782 regressed: fixed-overhead 2x]
#define CAPB 4608      // edge cap per bucket region (mean 4092, sigma 64 -> +8 sigma)
#define EPB  4093      // edges per xpart chunk: ceil(1600000/391)
#define XEIT 8         // xpart stage iterations: 8*512 = 4096 >= EPB
#define NPW  257       // np_g stride per bucket

// unpack 8 fp16 (uint4) into 8 float accumulators
__device__ __forceinline__ void acc8h(float* acc, uint4 v) {
    const __half2* p = reinterpret_cast<const __half2*>(&v);
#pragma unroll
    for (int q = 0; q < 4; q++) {
        float2 f = __half22float2(p[q]);
        acc[2*q]   += f.x;
        acc[2*q+1] += f.y;
    }
}
// unpack 4 fp16 (uint2) into 4 float accumulators
__device__ __forceinline__ void acc4h(float* acc, uint2 v) {
    const __half2* p = reinterpret_cast<const __half2*>(&v);
#pragma unroll
    for (int q = 0; q < 2; q++) {
        float2 f = __half22float2(p[q]);
        acc[2*q]   += f.x;
        acc[2*q+1] += f.y;
    }
}

// ====== kernel 1: node-transform (x@W1a -> fp16) + write-coalesced partition ======
// r18-proven: wave-shfl scan, lane-pair projection, bucket-sorted write-out
__global__ __launch_bounds__(512) void xpart_k(
    const float* __restrict__ x, const float* __restrict__ W1a,
    uint4* __restrict__ xw1h, const int* __restrict__ ei,
    int* __restrict__ gcursor, int* __restrict__ pairs) {
    __shared__ float sW[F0 * F1];
    __shared__ int hist[512];              // counts -> excl (reused)
    __shared__ int gbase[512];
    __shared__ int lcur[512];
    __shared__ int wsum[8];
    __shared__ int lpk[4096];              // chunk edges, bucket-sorted (packed)
    __shared__ unsigned short lb[4096];    // bucket id per sorted edge
    int t = threadIdx.x, c = blockIdx.x;
    int lane = t & 63, w = t >> 6;
    for (int i = t; i < F0 * F1; i += 512) sW[i] = W1a[i];
    hist[t] = 0;
    __syncthreads();

    // --- stage src+dst in registers + chunk histogram ---
    int base = c * EPB;
    int dreg[XEIT], sreg[XEIT];
#pragma unroll
    for (int it = 0; it < XEIT; it++) {
        int li = it * 512 + t;
        int i = base + li;
        dreg[it] = -1;
        if (li < EPB && i < N_EDGES) {
            sreg[it] = ei[i];
            int d = ei[N_EDGES + i];
            dreg[it] = d;
            atomicAdd(&hist[d >> BSH], 1);
        }
    }

    // --- node projection: lane pair (2s,2s+1) per node; lane h holds xi half ---
    {
        int h = t & 1, s = t >> 1;
        int n = c * 256 + s;
        if (n < N_NODES) {
            const float4* xp = reinterpret_cast<const float4*>(x) + n * 8 + h * 4;
            float xi[16];
#pragma unroll
            for (int q = 0; q < 4; q++) {
                float4 v = xp[q];
                xi[4*q] = v.x; xi[4*q+1] = v.y; xi[4*q+2] = v.z; xi[4*q+3] = v.w;
            }
            float o[F1];
#pragma unroll
            for (int j = 0; j < F1; j++) {
                float s2 = 0.0f;
#pragma unroll
                for (int k = 0; k < 16; k++) s2 += xi[k] * sW[(16*h + k) * F1 + j];
                o[j] = s2;
            }
#pragma unroll
            for (int j = 0; j < F1; j++) o[j] += __shfl_xor(o[j], 1); // pair-combine
            union { __half2 h2[4]; uint4 u4; } pk;
#pragma unroll
            for (int jj = 0; jj < 4; jj++)
                pk.h2[jj] = __float22half2_rn(make_float2(o[8*h + 2*jj],
                                                          o[8*h + 2*jj + 1]));
            xw1h[n * 2 + h] = pk.u4;       // 16B/lane, pair-coalesced
        }
    }
    __syncthreads();

    // --- wave-shfl inclusive scan of hist (512 wide) ---
    int cntb = hist[t];
    int v = cntb;
#pragma unroll
    for (int off = 1; off < 64; off <<= 1) {
        int u = __shfl_up(v, off);
        if (lane >= off) v += u;
    }
    if (lane == 63) wsum[w] = v;
    __syncthreads();
    int woff = 0;
    for (int i = 0; i < w; i++) woff += wsum[i];
    int ex = v + woff - cntb;              // exclusive prefix
    lcur[t] = ex;
    gbase[t] = (t < NBUK) ? (t * CAPB + (cntb ? atomicAdd(&gcursor[t], cntb) : 0))
                          : 0;
    hist[t] = ex;                          // hist[] now holds excl[]
    __syncthreads();

    // --- place staged edges into LDS, sorted by bucket (pure LDS ops) ---
#pragma unroll
    for (int it = 0; it < XEIT; it++) {
        int d = dreg[it];
        if (d >= 0) {
            int b = d >> BSH;
            int slot = atomicAdd(&lcur[b], 1);
            lpk[slot] = ((d & (BSZ - 1)) << 17) | sreg[it];
            lb[slot] = (unsigned short)b;
        }
    }
    __syncthreads();

    // --- coalesced write-out: consecutive i -> consecutive addr within runs ---
    int tot = min(EPB, N_EDGES - base);
    for (int i = t; i < tot; i += 512) {
        int b = lb[i];
        int gpos = gbase[b] + (i - hist[b]);
        if (gpos < (b + 1) * CAPB)         // overflow guard (~never taken)
            pairs[gpos] = lpk[i];
    }
}

// ==== kernel 2: per-bucket counting sort (LDS, double-buffered) + gin1 ====
// r18-proven; r20 delta: gather unrolled to 8 rows in flight (1 wait-round/node)
__global__ __launch_bounds__(512) void sortgin1_k(
    const uint4* __restrict__ xw1h, const int* __restrict__ pairs,
    const int* __restrict__ gcursor,
    const float* __restrict__ b1a, const float* __restrict__ W1b,
    const float* __restrict__ b1b, const float* __restrict__ W2a,
    uint2* __restrict__ h1wh, int* __restrict__ srcs,
    int* __restrict__ np_g) {
    __shared__ int hist[256];
    __shared__ int cur[256];
    __shared__ int np[BSZ + 1];
    __shared__ int wsum[4];
    __shared__ int srcs_l[CAPB];           // staged packed pairs
    __shared__ int srcs_s[CAPB];           // sorted srcs
    __shared__ float sW1b[F1 * F1];
    __shared__ float sW2a[F1 * F2];
    __shared__ float sb1a[F1], sb1b[F1];
    int t = threadIdx.x, b = blockIdx.x;
    int lane = t & 63, w = t >> 6;
    if (t < F1 * F1) sW1b[t] = W1b[t];
    if (t < F1 * F2) sW2a[t] = W2a[t];
    if (t < F1) { sb1a[t] = b1a[t]; sb1b[t] = b1b[t]; }
    if (t < 256) hist[t] = 0;
    __syncthreads();

    int cnt = min(gcursor[b], CAPB);
    int pb = b * CAPB;
    // hist + stage packed pairs into LDS (single global read of pairs)
    for (int i = t; i < cnt; i += 512) {
        int p = pairs[pb + i];
        srcs_l[i] = p;
        atomicAdd(&hist[p >> 17], 1);
    }
    __syncthreads();

    // --- wave-shfl inclusive scan of hist (256 wide: waves 0-3) ---
    int cntv = (t < 256) ? hist[t] : 0;
    int v = cntv;
    if (t < 256) {
#pragma unroll
        for (int off = 1; off < 64; off <<= 1) {
            int u = __shfl_up(v, off);
            if (lane >= off) v += u;
        }
        if (lane == 63) wsum[w] = v;
    }
    __syncthreads();
    if (t < 256) {
        int woff = 0;
        for (int i = 0; i < w; i++) woff += wsum[i];
        int excl = v + woff - cntv;
        np[t] = excl;
        cur[t] = excl;
        np_g[b * NPW + t] = excl;
        if (t == 0) { np[BSZ] = cnt; np_g[b * NPW + BSZ] = cnt; }
    }
    __syncthreads();

    // scatter into second buffer (no read/write race, no register staging)
    for (int i = t; i < cnt; i += 512) {
        int p = srcs_l[i];
        int pos = atomicAdd(&cur[p >> 17], 1);
        srcs_s[pos] = p & 0x1FFFF;
    }
    __syncthreads();
    // coalesced persist for gin2: consecutive lanes -> consecutive addresses
    for (int i = t; i < cnt; i += 512) srcs[pb + i] = srcs_s[i];

    // ---- layer-1 gather: 2 lanes/node, 16B/lane, 8 rows in flight ----
    int h = t & 1, slot = t >> 1;
    int n = b * BSZ + slot;
    if (n >= N_NODES) return;
    int e  = np[slot];
    int e1 = np[slot + 1];

    float acc[8];
#pragma unroll
    for (int k = 0; k < 8; k++) acc[k] = 0.0f;
    for (; e + 8 <= e1; e += 8) {                 // 8 rows in flight
        uint4 v0 = xw1h[srcs_s[e + 0] * 2 + h];
        uint4 v1 = xw1h[srcs_s[e + 1] * 2 + h];
        uint4 v2 = xw1h[srcs_s[e + 2] * 2 + h];
        uint4 v3 = xw1h[srcs_s[e + 3] * 2 + h];
        uint4 v4 = xw1h[srcs_s[e + 4] * 2 + h];
        uint4 v5 = xw1h[srcs_s[e + 5] * 2 + h];
        uint4 v6 = xw1h[srcs_s[e + 6] * 2 + h];
        uint4 v7 = xw1h[srcs_s[e + 7] * 2 + h];
        acc8h(acc, v0); acc8h(acc, v1); acc8h(acc, v2); acc8h(acc, v3);
        acc8h(acc, v4); acc8h(acc, v5); acc8h(acc, v6); acc8h(acc, v7);
    }
    if (e + 4 <= e1) {
        uint4 v0 = xw1h[srcs_s[e + 0] * 2 + h];
        uint4 v1 = xw1h[srcs_s[e + 1] * 2 + h];
        uint4 v2 = xw1h[srcs_s[e + 2] * 2 + h];
        uint4 v3 = xw1h[srcs_s[e + 3] * 2 + h];
        acc8h(acc, v0); acc8h(acc, v1); acc8h(acc, v2); acc8h(acc, v3);
        e += 4;
    }
    for (; e < e1; e++) acc8h(acc, xw1h[srcs_s[e] * 2 + h]);
    acc8h(acc, xw1h[n * 2 + h]);                  // self term

    float u[8];
#pragma unroll
    for (int k = 0; k < 8; k++) u[k] = fmaxf(acc[k] + sb1a[8*h + k], 0.0f);

    float p[F1];
#pragma unroll
    for (int j = 0; j < F1; j++) {
        float s = 0.0f;
#pragma unroll
        for (int k = 0; k < 8; k++) s += u[k] * sW1b[(8*h + k) * F1 + j];
        p[j] = s;
    }
#pragma unroll
    for (int j = 0; j < F1; j++) p[j] += __shfl_xor(p[j], 1);   // pair-combine
    float hh[F1];
#pragma unroll
    for (int j = 0; j < F1; j++) hh[j] = fmaxf(p[j] + sb1b[j], 0.0f); // relu∘relu

    float o[4];                                   // lane h owns outputs 4h..4h+3
#pragma unroll
    for (int jj = 0; jj < 4; jj++) {
        int j = 4*h + jj;
        float s = 0.0f;
#pragma unroll
        for (int k = 0; k < F1; k++) s += hh[k] * sW2a[k * F2 + j];
        o[jj] = s;
    }
    union { __half2 h2[2]; uint2 u2; } pk;
    pk.h2[0] = __float22half2_rn(make_float2(o[0], o[1]));
    pk.h2[1] = __float22half2_rn(make_float2(o[2], o[3]));
    h1wh[n * 2 + h] = pk.u2;                      // 8B/lane, pair-coalesced
}

// ==== kernel 3: layer-2 gather fp16 (2 lanes/node, 8 rows in flight) + pool ====
__global__ __launch_bounds__(256) void gin2pool_k(
    const uint2* __restrict__ h1wh, const int* __restrict__ np_g,
    const int* __restrict__ srcs, const float* __restrict__ b2a,
    const float* __restrict__ W2b, const float* __restrict__ b2b,
    const int* __restrict__ batch, float* __restrict__ gsum,
    float* __restrict__ gcnt) {
    __shared__ float sW2b[F2 * F2];
    __shared__ float sb2a[F2];
    __shared__ float sb2b[F2];
    __shared__ float ls[NGRAPH * F2];   // 512 > blockDim -> strided loops (r5 lesson)
    __shared__ float lc[NGRAPH];
    int t = threadIdx.x;
    if (t < F2 * F2) sW2b[t] = W2b[t];
    if (t < F2) { sb2a[t] = b2a[t]; sb2b[t] = b2b[t]; }
    for (int i = t; i < NGRAPH * F2; i += 256) ls[i] = 0.0f;
    if (t < NGRAPH) lc[t] = 0.0f;
    __syncthreads();

    int h = t & 1, slot = t >> 1;                 // 128 nodes per block
    int n = blockIdx.x * 128 + slot;
    if (n < N_NODES) {
        int b = n >> BSH, sl = n & (BSZ - 1);
        int pb = b * CAPB;
        int e  = pb + np_g[b * NPW + sl];
        int e1 = pb + np_g[b * NPW + sl + 1];

        float acc[4];
#pragma unroll
        for (int k = 0; k < 4; k++) acc[k] = 0.0f;
        for (; e + 8 <= e1; e += 8) {             // 8 rows in flight
            uint2 v0 = h1wh[srcs[e + 0] * 2 + h];
            uint2 v1 = h1wh[srcs[e + 1] * 2 + h];
            uint2 v2 = h1wh[srcs[e + 2] * 2 + h];
            uint2 v3 = h1wh[srcs[e + 3] * 2 + h];
            uint2 v4 = h1wh[srcs[e + 4] * 2 + h];
            uint2 v5 = h1wh[srcs[e + 5] * 2 + h];
            uint2 v6 = h1wh[srcs[e + 6] * 2 + h];
            uint2 v7 = h1wh[srcs[e + 7] * 2 + h];
            acc4h(acc, v0); acc4h(acc, v1); acc4h(acc, v2); acc4h(acc, v3);
            acc4h(acc, v4); acc4h(acc, v5); acc4h(acc, v6); acc4h(acc, v7);
        }
        if (e + 4 <= e1) {
            uint2 v0 = h1wh[srcs[e + 0] * 2 + h];
            uint2 v1 = h1wh[srcs[e + 1] * 2 + h];
            uint2 v2 = h1wh[srcs[e + 2] * 2 + h];
            uint2 v3 = h1wh[srcs[e + 3] * 2 + h];
            acc4h(acc, v0); acc4h(acc, v1); acc4h(acc, v2); acc4h(acc, v3);
            e += 4;
        }
        for (; e < e1; e++) acc4h(acc, h1wh[srcs[e] * 2 + h]);
        acc4h(acc, h1wh[n * 2 + h]);              // self term

        float u[4];
#pragma unroll
        for (int k = 0; k < 4; k++) u[k] = fmaxf(acc[k] + sb2a[4*h + k], 0.0f);

        float p[F2];
#pragma unroll
        for (int j = 0; j < F2; j++) {
            float s = 0.0f;
#pragma unroll
            for (int k = 0; k < 4; k++) s += u[k] * sW2b[(4*h + k) * F2 + j];
            p[j] = s;
        }
#pragma unroll
        for (int j = 0; j < F2; j++) p[j] += __shfl_xor(p[j], 1);

        int g = batch[n];
#pragma unroll
        for (int jj = 0; jj < 4; jj++) {          // lane h flushes feats 4h..4h+3
            int j = 4*h + jj;
            float v = fmaxf(p[j] + sb2b[j], 0.0f);
            atomicAdd(&ls[g * F2 + j], v);
        }
        if (h == 0) atomicAdd(&lc[g], 1.0f);
    }
    __syncthreads();
    for (int i = t; i < NGRAPH * F2; i += 256)
        if (ls[i] != 0.0f) atomicAdd(&gsum[i], ls[i]);
    if (t < NGRAPH && lc[t] != 0.0f) atomicAdd(&gcnt[t], lc[t]);
}

// ---------------- final: pooled -> FC -> log_softmax ----------------
__global__ void final_k(const float* __restrict__ gsum,
                        const float* __restrict__ gcnt,
                        const float* __restrict__ Wfc, const float* __restrict__ bfc,
                        float* __restrict__ out) {
    int g = threadIdx.x;
    if (g >= NGRAPH) return;
    float cnt = fmaxf(gcnt[g], 1.0f);
    float p[F2];
#pragma unroll
    for (int f = 0; f < F2; f++) p[f] = gsum[g * F2 + f] / cnt;
    float l[NCLS];
#pragma unroll
    for (int c = 0; c < NCLS; c++) {
        float s = bfc[c];
#pragma unroll
        for (int f = 0; f < F2; f++) s += p[f] * Wfc[f * NCLS + c];
        l[c] = s;
    }
    float m = -INFINITY;
#pragma unroll
    for (int c = 0; c < NCLS; c++) m = fmaxf(m, l[c]);
    float s = 0.0f;
#pragma unroll
    for (int c = 0; c < NCLS; c++) s += expf(l[c] - m);
    float lse = m + logf(s);
#pragma unroll
    for (int c = 0; c < NCLS; c++) out[g * NCLS + c] = l[c] - lse;
}

extern "C" void kernel_launch(void* const* d_in, const int* in_sizes, int n_in,
                              void* d_out, int out_size, void* d_ws, size_t ws_size,
                              hipStream_t stream) {
    const float* x    = (const float*)d_in[0];
    const int*   ei   = (const int*)d_in[1];   // [2, N_EDGES]
    const int*   batch= (const int*)d_in[2];   // [N_NODES], sorted
    const float* W1a  = (const float*)d_in[3];
    const float* b1a  = (const float*)d_in[4];
    const float* W1b  = (const float*)d_in[5];
    const float* b1b  = (const float*)d_in[6];
    const float* W2a  = (const float*)d_in[7];
    const float* b2a  = (const float*)d_in[8];
    const float* W2b  = (const float*)d_in[9];
    const float* b2b  = (const float*)d_in[10];
    const float* Wfc  = (const float*)d_in[11];
    const float* bfc  = (const float*)d_in[12];
    float* out = (float*)d_out;

    // workspace layout (4-byte units), ~20 MB
    float* ws      = (float*)d_ws;
    uint4* xw1h    = (uint4*)ws;                           // N_NODES*2 uint4 (fp16)
    uint2* h1wh    = (uint2*)(ws + (size_t)N_NODES * 8);   // N_NODES*2 uint2 (fp16)
    int*   pairs   = (int*)(ws + (size_t)N_NODES * 12);    // NBUK*CAPB = 1801728
    int*   srcs    = pairs + (size_t)NBUK * CAPB;          // NBUK*CAPB
    int*   np_g    = srcs + (size_t)NBUK * CAPB;           // NBUK*NPW = 100487
    int*   gcursor = np_g + (size_t)NBUK * NPW + 9;        // 512   (memset)
    float* gsum    = (float*)(gcursor + 512);              // 512   (memset)
    float* gcnt    = gsum + NGRAPH * F2;                   // 64    (memset)

    // one tiny memset: gcursor + gsum + gcnt adjacent
    hipMemsetAsync(gcursor, 0, (512 + NGRAPH * F2 + NGRAPH) * sizeof(int), stream);

    xpart_k<<<NBUK, 512, 0, stream>>>(x, W1a, xw1h, ei, gcursor, pairs);
    sortgin1_k<<<NBUK, 512, 0, stream>>>(xw1h, pairs, gcursor,
                                         b1a, W1b, b1b, W2a,
                                         h1wh, srcs, np_g);
    gin2pool_k<<<(N_NODES + 127) / 128, 256, 0, stream>>>(h1wh, np_g, srcs,
                                                          b2a, W2b, b2b, batch,
                                                          gsum, gcnt);
    final_k<<<1, 64, 0, stream>>>(gsum, gcnt, Wfc, bfc, out);
}